// Round 2
// baseline (36.905 us; speedup 1.0000x reference)
//
#include <hip/hip_runtime.h>

constexpr int B  = 4;
constexpr int K  = 256;
constexpr int F  = 128;
constexpr int E2 = 256;   // output dim of each of s1/s2
constexpr int ET = 512;   // s1 | s2 concatenated

// ---------------------------------------------------------------------------
// K1: S[b][k][e2] = sum_f x[b,k,f] * Wsel[e2,f]  (+ b_lin for e2>=256)
// grid (ET/32, K/32, B) = (16,8,4) = 512 blocks (2 blocks/CU), 256 threads
// ---------------------------------------------------------------------------
__global__ __launch_bounds__(256) void k1_gemm(const float* __restrict__ x,
                                               const float* __restrict__ W,
                                               const float* __restrict__ bl,
                                               float* __restrict__ S) {
    __shared__ float xt[32][132];   // +4 pad
    __shared__ float wt[32][132];
    const int b  = blockIdx.z;
    const int k0 = blockIdx.y * 32;
    const int e0 = blockIdx.x * 32;
    const int tid = threadIdx.x;

    const int col4 = (tid & 31) * 4;
    const int rsub = tid >> 5;               // 0..7
#pragma unroll
    for (int p = 0; p < 4; ++p) {
        int row = p * 8 + rsub;
        *(float4*)&xt[row][col4] =
            *(const float4*)&x[(b * K + k0 + row) * F + col4];
        int eg = e0 + row;
        int wr = eg & (E2 - 1);
        int fb = (eg >= E2) ? F : 0;
        *(float4*)&wt[row][col4] =
            *(const float4*)&W[wr * (2 * F) + fb + col4];
    }
    __syncthreads();

    const int es = tid & 15;                 // e = e0 + es + 16*t
    const int kb = tid >> 4;                 // k = k0 + kb + 16*kk
    float acc[2][2] = {};
    for (int f4 = 0; f4 < F; f4 += 4) {
        float4 x0 = *(const float4*)&xt[kb][f4];
        float4 x1 = *(const float4*)&xt[kb + 16][f4];
        float4 w0 = *(const float4*)&wt[es][f4];
        float4 w1 = *(const float4*)&wt[es + 16][f4];
        acc[0][0] += x0.x * w0.x + x0.y * w0.y + x0.z * w0.z + x0.w * w0.w;
        acc[0][1] += x0.x * w1.x + x0.y * w1.y + x0.z * w1.z + x0.w * w1.w;
        acc[1][0] += x1.x * w0.x + x1.y * w0.y + x1.z * w0.z + x1.w * w0.w;
        acc[1][1] += x1.x * w1.x + x1.y * w1.y + x1.z * w1.z + x1.w * w1.w;
    }

    const bool isS2 = (e0 >= E2);            // block-uniform
#pragma unroll
    for (int t = 0; t < 2; ++t) {
        int   eg  = e0 + es + 16 * t;
        float add = isS2 ? bl[eg - E2] : 0.f;
        S[(b * K + k0 + kb) * ET + eg]      = acc[0][t] + add;
        S[(b * K + k0 + kb + 16) * ET + eg] = acc[1][t] + add;
    }
}

// ---------------------------------------------------------------------------
// KB (fused): scores + softmax + PV + sigmoid.
//   E[i][j] = sum_e a[e]*leakyrelu(s1[i,e]+s2[j,e]) + bias[i,j]
//   leakyrelu(p) = 0.6p + 0.4|p|
// grid (K/4, B) = (64,4) = 256 blocks, 256 threads.
// Block owns 4 i-rows. The 4 waves split the e-dim in quarters (keeps 4x i
// reuse per lane-varying s2 read); partial scores reduced via LDS. Then wave
// w does row i0+w's softmax in-register; PV splits j across waves (x read
// once per block), cross-wave reduce via LDS, sigmoid, store.
// ---------------------------------------------------------------------------
__global__ __launch_bounds__(256) void kb_fused(const float* __restrict__ S,
                                                const float* __restrict__ x,
                                                const float* __restrict__ a,
                                                const float* __restrict__ bias,
                                                float* __restrict__ out) {
    __shared__ float s2t[2][32][260];    // double-buffered j-tile (pad 260)
    __shared__ float s1t[4][260];
    __shared__ float av6[E2], av4[E2];
    __shared__ float scp[4][4][K];       // [e-quarter wave][i-sub][j] partials
    __shared__ float p_lds[K][4];        // [j][i-sub]
    __shared__ float yp[4][4][F];        // [wave][i-sub][f]
    __shared__ float rinv_lds[4];
    const int b    = blockIdx.y;
    const int i0   = blockIdx.x * 4;
    const int tid  = threadIdx.x;
    const int w    = tid >> 6;
    const int lane = tid & 63;
    const int jl   = lane & 31;
    const int eh   = lane >> 5;

    { float av = a[tid]; av6[tid] = 0.6f * av; av4[tid] = 0.4f * av; }
    {   // stage the 4 s1 rows (1024 floats)
        int row = tid >> 6, c4 = (tid & 63) * 4;
        *(float4*)&s1t[row][c4] =
            *(const float4*)&S[(b * K + i0 + row) * ET + c4];
    }
#pragma unroll
    for (int p = 0; p < 8; ++p) {        // stage s2 tile 0
        int idx = p * 256 + tid;
        int row = idx >> 6, c4 = (idx & 63) * 4;
        *(float4*)&s2t[0][row][c4] =
            *(const float4*)&S[(b * K + row) * ET + E2 + c4];
    }
    __syncthreads();

    // ---- score phase: wave w covers e in [64w, 64w+64); lane: (jl, eh)
    float er[4][8];
    const int eb = w * 64 + eh * 32;
#pragma unroll
    for (int jt = 0; jt < 8; ++jt) {
        const int cur = jt & 1;
        if (jt < 7) {                    // stage next tile into other buffer
            int j0n = (jt + 1) * 32;
#pragma unroll
            for (int p = 0; p < 8; ++p) {
                int idx = p * 256 + tid;
                int row = idx >> 6, c4 = (idx & 63) * 4;
                *(float4*)&s2t[cur ^ 1][row][c4] =
                    *(const float4*)&S[(b * K + j0n + row) * ET + E2 + c4];
            }
        }
        float ac[4] = {0.f, 0.f, 0.f, 0.f};
#pragma unroll
        for (int m = 0; m < 8; ++m) {
            const int e = eb + m * 4;
            float4 sv  = *(const float4*)&s2t[cur][jl][e];  // lane-varying
            float4 c6  = *(const float4*)&av6[e];           // 2-addr bcast
            float4 c4v = *(const float4*)&av4[e];
#pragma unroll
            for (int is = 0; is < 4; ++is) {
                float4 s1v = *(const float4*)&s1t[is][e];   // 2-addr bcast
                float p0 = s1v.x + sv.x;
                float p1 = s1v.y + sv.y;
                float p2 = s1v.z + sv.z;
                float p3 = s1v.w + sv.w;
                ac[is] += c6.x * p0 + c4v.x * fabsf(p0);
                ac[is] += c6.y * p1 + c4v.y * fabsf(p1);
                ac[is] += c6.z * p2 + c4v.z * fabsf(p2);
                ac[is] += c6.w * p3 + c4v.w * fabsf(p3);
            }
        }
#pragma unroll
        for (int is = 0; is < 4; ++is) er[is][jt] = ac[is];
        __syncthreads();                 // staging done + cur fully consumed
    }

    // combine the two e-halves inside the wave, write e-quarter partials
#pragma unroll
    for (int is = 0; is < 4; ++is)
#pragma unroll
        for (int jt = 0; jt < 8; ++jt)
            er[is][jt] += __shfl_xor(er[is][jt], 32);
    if (eh == 0) {
#pragma unroll
        for (int is = 0; is < 4; ++is)
#pragma unroll
            for (int jt = 0; jt < 8; ++jt)
                scp[w][is][jt * 32 + jl] = er[is][jt];
    }
    __syncthreads();

    // ---- softmax of row i = i0 + w (unnormalized; 1/sum applied at end)
    const int i = i0 + w;
    float sc[4];
#pragma unroll
    for (int mm = 0; mm < 4; ++mm) {
        int j = mm * 64 + lane;
        sc[mm] = scp[0][w][j] + scp[1][w][j] + scp[2][w][j] + scp[3][w][j]
               + bias[i * K + j];
    }
    float mx = fmaxf(fmaxf(sc[0], sc[1]), fmaxf(sc[2], sc[3]));
#pragma unroll
    for (int off = 32; off > 0; off >>= 1) mx = fmaxf(mx, __shfl_xor(mx, off));
    float pm[4], ssum = 0.f;
#pragma unroll
    for (int mm = 0; mm < 4; ++mm) { pm[mm] = __expf(sc[mm] - mx); ssum += pm[mm]; }
#pragma unroll
    for (int off = 32; off > 0; off >>= 1) ssum += __shfl_xor(ssum, off);
    if (lane == 0) rinv_lds[w] = 1.f / ssum;
#pragma unroll
    for (int mm = 0; mm < 4; ++mm) p_lds[mm * 64 + lane][w] = pm[mm];
    __syncthreads();

    // ---- PV: y[i][f] = sum_j p[i][j] * x[b][j][f]; wave w takes 64 j's
    float acc[4][2] = {};
    const float* xb = &x[(size_t)(b * K) * F];
#pragma unroll 4
    for (int jj = 0; jj < 64; ++jj) {
        int j = w * 64 + jj;
        float2 xv = *(const float2*)&xb[j * F + lane * 2];
        float4 pj = *(const float4*)&p_lds[j][0];    // broadcast
        acc[0][0] += pj.x * xv.x;  acc[0][1] += pj.x * xv.y;
        acc[1][0] += pj.y * xv.x;  acc[1][1] += pj.y * xv.y;
        acc[2][0] += pj.z * xv.x;  acc[2][1] += pj.z * xv.y;
        acc[3][0] += pj.w * xv.x;  acc[3][1] += pj.w * xv.y;
    }
#pragma unroll
    for (int ii = 0; ii < 4; ++ii) {
        yp[w][ii][lane * 2]     = acc[ii][0];
        yp[w][ii][lane * 2 + 1] = acc[ii][1];
    }
    __syncthreads();

    // ---- cross-wave reduce + sigmoid + store (512 outputs, 2 per thread)
#pragma unroll
    for (int r = 0; r < 2; ++r) {
        int id = r * 256 + tid;
        int ii = id >> 7;
        int f  = id & 127;
        float y = yp[0][ii][f] + yp[1][ii][f] + yp[2][ii][f] + yp[3][ii][f];
        float z = y * rinv_lds[ii];
        out[(b * K + i0 + ii) * F + f] = 1.f / (1.f + __expf(-z));
    }
}

// ---------------------------------------------------------------------------
extern "C" void kernel_launch(void* const* d_in, const int* in_sizes, int n_in,
                              void* d_out, int out_size, void* d_ws, size_t ws_size,
                              hipStream_t stream) {
    const float* x    = (const float*)d_in[0];   // (4,256,128)
    const float* W    = (const float*)d_in[1];   // (256,256)
    const float* bl   = (const float*)d_in[2];   // (256,)
    const float* a    = (const float*)d_in[3];   // (256,)
    const float* bias = (const float*)d_in[4];   // (256,256)
    float* out = (float*)d_out;                  // (4,256,128)

    float* S = (float*)d_ws;                     // B*K*ET fp32 = 2 MB

    k1_gemm <<<dim3(ET / 32, K / 32, B), 256, 0, stream>>>(x, W, bl, S);
    kb_fused<<<dim3(K / 4, B),           256, 0, stream>>>(S, x, a, bias, out);
}

// Round 3
// 31.382 us; speedup vs baseline: 1.1760x; 1.1760x over previous
//
#include <hip/hip_runtime.h>

constexpr int B  = 4;
constexpr int K  = 256;
constexpr int F  = 128;
constexpr int E2 = 256;   // output dim of each of s1/s2
constexpr int ET = 512;   // s1 | s2 concatenated in S

// ---------------------------------------------------------------------------
// K1: S[b][k][e2] = sum_f x[b,k,f] * Wsel[e2,f]  (+ b_lin for e2>=256)
//     e2 <  256 : W[e2, 0:128]          (s1)
//     e2 >= 256 : W[e2-256, 128:256] + b_lin[e2-256]   (s2', b_lin folded)
// grid (16,8,4) = 512 blocks (2/CU), 256 threads
// ---------------------------------------------------------------------------
__global__ __launch_bounds__(256) void k1_gemm(const float* __restrict__ x,
                                               const float* __restrict__ W,
                                               const float* __restrict__ bl,
                                               float* __restrict__ S) {
    __shared__ float xt[32][132];   // +4 pad
    __shared__ float wt[32][132];
    const int b  = blockIdx.z;
    const int k0 = blockIdx.y * 32;
    const int e0 = blockIdx.x * 32;
    const int tid = threadIdx.x;

    const int col4 = (tid & 31) * 4;
    const int rsub = tid >> 5;               // 0..7
#pragma unroll
    for (int p = 0; p < 4; ++p) {
        int row = p * 8 + rsub;
        *(float4*)&xt[row][col4] =
            *(const float4*)&x[(b * K + k0 + row) * F + col4];
        int eg = e0 + row;
        int wr = eg & (E2 - 1);
        int fb = (eg >= E2) ? F : 0;
        *(float4*)&wt[row][col4] =
            *(const float4*)&W[wr * (2 * F) + fb + col4];
    }
    __syncthreads();

    const int es = tid & 15;                 // e = e0 + es + 16*t
    const int kb = tid >> 4;                 // k = k0 + kb + 16*kk
    float acc[2][2] = {};
    for (int f4 = 0; f4 < F; f4 += 4) {
        float4 x0 = *(const float4*)&xt[kb][f4];
        float4 x1 = *(const float4*)&xt[kb + 16][f4];
        float4 w0 = *(const float4*)&wt[es][f4];
        float4 w1 = *(const float4*)&wt[es + 16][f4];
        acc[0][0] += x0.x * w0.x + x0.y * w0.y + x0.z * w0.z + x0.w * w0.w;
        acc[0][1] += x0.x * w1.x + x0.y * w1.y + x0.z * w1.z + x0.w * w1.w;
        acc[1][0] += x1.x * w0.x + x1.y * w0.y + x1.z * w0.z + x1.w * w0.w;
        acc[1][1] += x1.x * w1.x + x1.y * w1.y + x1.z * w1.z + x1.w * w1.w;
    }

    const bool isS2 = (e0 >= E2);            // block-uniform
#pragma unroll
    for (int t = 0; t < 2; ++t) {
        int   eg  = e0 + es + 16 * t;
        float add = isS2 ? bl[eg - E2] : 0.f;
        S[(b * K + k0 + kb) * ET + eg]      = acc[0][t] + add;
        S[(b * K + k0 + kb + 16) * ET + eg] = acc[1][t] + add;
    }
}

// ---------------------------------------------------------------------------
// K2': E'[i,j] = v[j] + sum_e 0.4*a[e]*|s1[i,e]+s2'[j,e]| + bias[i,j]
//      (u[i] = sum_e 0.6 a e s1[i,e] is constant per softmax row -> dropped;
//       v[j] = sum_e 0.6 a[e] s2'[j,e] = 1.5 * sum_e a4[e] s2'[j,e])
// grid (K/64, K/8, B) = (4,32,4) = 512 blocks (2/CU), 256 threads.
// lane = j (64), wave w = e-quarter (64 e's). s2-chunk + 0.4a-chunk in VGPRs,
// s1 i-tile in LDS (broadcast reads). Inner loop: pure VALU, 2 instr/element.
// ---------------------------------------------------------------------------
__global__ __launch_bounds__(256) void k2_score(const float* __restrict__ S,
                                                const float* __restrict__ a,
                                                const float* __restrict__ bias,
                                                float* __restrict__ Eo) {
    __shared__ float s1t[8][256];        // i-tile of s1 (broadcast-read)
    __shared__ float scp[4][8][64];      // [e-quarter][i-sub][j] partials
    __shared__ float vp[4][64];          // [e-quarter][j] v-partials
    const int b    = blockIdx.z;
    const int i0   = blockIdx.y * 8;
    const int j0   = blockIdx.x * 64;
    const int tid  = threadIdx.x;
    const int w    = tid >> 6;           // e-quarter
    const int lane = tid & 63;           // j - j0
    const int e0   = w * 64;

    // stage s1 tile: 8 rows x 256 e = 512 float4
#pragma unroll
    for (int p = 0; p < 2; ++p) {
        int id = p * 256 + tid;
        int row = id >> 6, c4 = (id & 63) * 4;
        *(float4*)&s1t[row][c4] =
            *(const float4*)&S[(b * K + i0 + row) * ET + c4];
    }

    // a4 chunk (broadcast load) and s2 chunk (per-lane) into registers
    float a4r[64], s2r[64];
    {
        const float* s2p = &S[((size_t)(b * K + j0 + lane)) * ET + E2 + e0];
#pragma unroll
        for (int m = 0; m < 16; ++m) {
            float4 av = *(const float4*)&a[e0 + m * 4];
            float4 sv = *(const float4*)&s2p[m * 4];
            a4r[m * 4 + 0] = 0.4f * av.x;  s2r[m * 4 + 0] = sv.x;
            a4r[m * 4 + 1] = 0.4f * av.y;  s2r[m * 4 + 1] = sv.y;
            a4r[m * 4 + 2] = 0.4f * av.z;  s2r[m * 4 + 2] = sv.z;
            a4r[m * 4 + 3] = 0.4f * av.w;  s2r[m * 4 + 3] = sv.w;
        }
    }
    // v partial for this e-quarter (scale by 1.5 at combine)
    float vpt = 0.f;
#pragma unroll
    for (int e = 0; e < 64; ++e) vpt = fmaf(a4r[e], s2r[e], vpt);
    vp[w][lane] = vpt;
    __syncthreads();

    // main: 8 i-rows x 64 e, 2 VALU per element, two acc chains
#pragma unroll
    for (int ii = 0; ii < 8; ++ii) {
        float a0 = 0.f, a1 = 0.f;
#pragma unroll
        for (int m = 0; m < 16; ++m) {
            float4 s1v = *(const float4*)&s1t[ii][e0 + m * 4];  // broadcast
            float t0 = s2r[m * 4 + 0] + s1v.x;
            float t1 = s2r[m * 4 + 1] + s1v.y;
            float t2 = s2r[m * 4 + 2] + s1v.z;
            float t3 = s2r[m * 4 + 3] + s1v.w;
            a0 = fmaf(a4r[m * 4 + 0], fabsf(t0), a0);
            a1 = fmaf(a4r[m * 4 + 1], fabsf(t1), a1);
            a0 = fmaf(a4r[m * 4 + 2], fabsf(t2), a0);
            a1 = fmaf(a4r[m * 4 + 3], fabsf(t3), a1);
        }
        scp[w][ii][lane] = a0 + a1;
    }
    __syncthreads();

    // combine e-quarters + v + bias, write E' (2 outputs/thread)
#pragma unroll
    for (int r = 0; r < 2; ++r) {
        int id = r * 256 + tid;
        int ii = id >> 6, jl = id & 63;
        float s = scp[0][ii][jl] + scp[1][ii][jl]
                + scp[2][ii][jl] + scp[3][ii][jl];
        float v = 1.5f * (vp[0][jl] + vp[1][jl] + vp[2][jl] + vp[3][jl]);
        int ig = i0 + ii, jg = j0 + jl;
        Eo[(b * K + ig) * K + jg] = s + v + bias[ig * K + jg];
    }
}

// ---------------------------------------------------------------------------
// K3: softmax over j (in-register, per wave) + PV + sigmoid
// grid (K/4, B) = (64,4) = 256 blocks, 256 threads
// ---------------------------------------------------------------------------
__global__ __launch_bounds__(256) void k3_softmax_pv(const float* __restrict__ Ein,
                                                     const float* __restrict__ x,
                                                     float* __restrict__ out) {
    __shared__ float p_lds[K][4];        // [j][i-sub]
    __shared__ float yp[4][4][F];        // [wave][i-sub][f]
    __shared__ float rinv_lds[4];
    const int b   = blockIdx.y;
    const int i0  = blockIdx.x * 4;
    const int tid = threadIdx.x;
    const int w   = tid >> 6;
    const int lane = tid & 63;

    // ---- softmax of row i = i0 + w (unnormalized; 1/sum applied at end)
    const int i = i0 + w;
    const float* Erow = &Ein[(b * K + i) * K];
    float er[4];
#pragma unroll
    for (int m = 0; m < 4; ++m) er[m] = Erow[m * 64 + lane];
    float mx = fmaxf(fmaxf(er[0], er[1]), fmaxf(er[2], er[3]));
#pragma unroll
    for (int off = 32; off > 0; off >>= 1) mx = fmaxf(mx, __shfl_xor(mx, off));
    float pm[4], s = 0.f;
#pragma unroll
    for (int m = 0; m < 4; ++m) { pm[m] = __expf(er[m] - mx); s += pm[m]; }
#pragma unroll
    for (int off = 32; off > 0; off >>= 1) s += __shfl_xor(s, off);
    if (lane == 0) rinv_lds[w] = 1.f / s;
#pragma unroll
    for (int m = 0; m < 4; ++m) p_lds[m * 64 + lane][w] = pm[m];
    __syncthreads();

    // ---- PV: y[i][f] = sum_j p[i][j] * x[b][j][f]; wave w takes 64 j's
    float acc[4][2] = {};
    const float* xb = &x[(size_t)(b * K) * F];
#pragma unroll 4
    for (int jj = 0; jj < 64; ++jj) {
        int j = w * 64 + jj;
        float2 xv = *(const float2*)&xb[j * F + lane * 2];
        float4 pj = *(const float4*)&p_lds[j][0];    // broadcast
        acc[0][0] += pj.x * xv.x;  acc[0][1] += pj.x * xv.y;
        acc[1][0] += pj.y * xv.x;  acc[1][1] += pj.y * xv.y;
        acc[2][0] += pj.z * xv.x;  acc[2][1] += pj.z * xv.y;
        acc[3][0] += pj.w * xv.x;  acc[3][1] += pj.w * xv.y;
    }
#pragma unroll
    for (int ii = 0; ii < 4; ++ii) {
        yp[w][ii][lane * 2]     = acc[ii][0];
        yp[w][ii][lane * 2 + 1] = acc[ii][1];
    }
    __syncthreads();

    // ---- cross-wave reduce + sigmoid + store (512 outputs, 2 per thread)
#pragma unroll
    for (int r = 0; r < 2; ++r) {
        int id = r * 256 + tid;
        int ii = id >> 7;
        int f  = id & 127;
        float y = yp[0][ii][f] + yp[1][ii][f] + yp[2][ii][f] + yp[3][ii][f];
        float z = y * rinv_lds[ii];
        out[(b * K + i0 + ii) * F + f] = 1.f / (1.f + __expf(-z));
    }
}

// ---------------------------------------------------------------------------
extern "C" void kernel_launch(void* const* d_in, const int* in_sizes, int n_in,
                              void* d_out, int out_size, void* d_ws, size_t ws_size,
                              hipStream_t stream) {
    const float* x    = (const float*)d_in[0];   // (4,256,128)
    const float* W    = (const float*)d_in[1];   // (256,256)
    const float* bl   = (const float*)d_in[2];   // (256,)
    const float* a    = (const float*)d_in[3];   // (256,)
    const float* bias = (const float*)d_in[4];   // (256,256)
    float* out = (float*)d_out;                  // (4,256,128)

    float* S = (float*)d_ws;                               // 2 MB
    float* E = (float*)((char*)d_ws + (size_t)B * K * ET * sizeof(float)); // 1 MB

    k1_gemm     <<<dim3(ET / 32, K / 32, B), 256, 0, stream>>>(x, W, bl, S);
    k2_score    <<<dim3(K / 64, K / 8, B),   256, 0, stream>>>(S, a, bias, E);
    k3_softmax_pv<<<dim3(K / 4, B),          256, 0, stream>>>(E, x, out);
}